// Round 5
// baseline (249.478 us; speedup 1.0000x reference)
//
#include <hip/hip_runtime.h>
#include <hip/hip_bf16.h>

#define MPTS 50000
#define NPTS 100000
#define HH 32
#define KK 15
#define KC 1024        // GEMM K dim: 64 c * 16 k (k=15 zero pad)

typedef __attribute__((ext_vector_type(8))) short short8;
typedef __attribute__((ext_vector_type(4))) short short4v;   // align 8
typedef __attribute__((ext_vector_type(4))) float floatx4;

static __device__ __forceinline__ unsigned short f2bf(float f) {
    __hip_bfloat16 h = __float2bfloat16(f);
    return *reinterpret_cast<unsigned short*>(&h);
}

static __device__ __forceinline__ short8 lds_load8(const unsigned short* p) {
    // 8-byte-aligned LDS load of 8 bf16 (2 x ds_read_b64)
    const short4v a = *(const short4v*)p;
    const short4v b = *(const short4v*)(p + 4);
    short8 r;
    r[0] = a[0]; r[1] = a[1]; r[2] = a[2]; r[3] = a[3];
    r[4] = b[0]; r[5] = b[1]; r[6] = b[2]; r[7] = b[3];
    return r;
}

// ---- prep 1: W''[d][c*16+k] = bf16(weights[k][c][d]), k=15 row zeroed (128 KB)
__global__ void prep_weights(const float* __restrict__ w, unsigned short* __restrict__ wbf) {
    const int i = blockIdx.x * 256 + threadIdx.x;       // 65536
    const int d = i >> 10, kc = i & (KC - 1);
    const int c = kc >> 4, k = kc & 15;
    const float v = (k < KK) ? w[k * 4096 + c * 64 + d] : 0.0f;
    wbf[i] = f2bf(v);
}

// ---- prep 2: exact numpy-pairwise-order row sums of s_feats (400 KB)
__global__ void prep_rowsum(const float* __restrict__ sf, float* __restrict__ rs) {
    const int t = blockIdx.x * 256 + threadIdx.x;
    const int row = t >> 1, p = t & 1;
    if (row >= NPTS) return;
    const float* base = sf + row * 64 + p * 4;
    float4 r = *(const float4*)base;
#pragma unroll
    for (int i = 1; i < 8; i++) {
        const float4 x = *(const float4*)(base + i * 8);
        r.x += x.x; r.y += x.y; r.z += x.z; r.w += x.w;
    }
    float sp = (r.x + r.y) + (r.z + r.w);
    sp += __shfl_xor(sp, 1);
    if (p == 0) rs[row] = sp;
}

// =======================================================================
// K1: gather + kernel-weights + MFMA-B; writes weighted (bf16, /cnt) to ws.
// Barrier-free m-loop: each wave owns 4 m's and a private stage buffer.
// LDS: q 192 + kp 240 + idx 2048 + w_lds 18432 + stage 18432 + inv 64
//    = 39408 B -> 4 blocks/CU (16 waves).
// =======================================================================
__global__ __launch_bounds__(256, 4) void k1_weighted(
    const float* __restrict__ q_points,
    const float* __restrict__ s_points,
    const float* __restrict__ s_feats,
    const int*   __restrict__ nbr,
    const float* __restrict__ kpts,
    const float* __restrict__ rowsum,
    unsigned short* __restrict__ wt,      // (chunk_rows, 1024) bf16
    int base_row)
{
    const int t    = threadIdx.x;
    const int lane = t & 63;
    const int wv   = t >> 6;
    const int l15  = lane & 15;
    const int lq   = lane >> 4;
    const int m0   = base_row + blockIdx.x * 16;
    const int lr0  = blockIdx.x * 16;          // local (chunk) row base

    __shared__ float q_lds[16][3];
    __shared__ float kp_lds[KK][4];
    __shared__ int   idx_lds[16][HH];
    __shared__ unsigned short w_lds[16][16][36];     // [m][k][h], stride 36 (2-way free)
    __shared__ unsigned short stage[4][64][36];      // per-wave [c][h] bf16, stride 36
    __shared__ float inv_lds[16];

    // ---------------- Phase A ----------------
    if (t < 16 * 3) q_lds[t / 3][t % 3] = q_points[m0 * 3 + t];
    if (t < KK * 3) kp_lds[t / 3][t % 3] = kpts[t];
    idx_lds[t >> 5][t & 31]         = nbr[m0 * HH + t];
    idx_lds[(t + 256) >> 5][t & 31] = nbr[m0 * HH + t + 256];
    __syncthreads();

    // kernel-point weights (k=15 zero pad)
#pragma unroll
    for (int s = 0; s < 2; s++) {
        const int it = s * 256 + t;
        const int m = it >> 5, h = it & 31;
        const int idx = idx_lds[m][h];
        float px = 1.0e6f, py = 1.0e6f, pz = 1.0e6f;
        if (idx < NPTS) {
            px = s_points[idx * 3 + 0];
            py = s_points[idx * 3 + 1];
            pz = s_points[idx * 3 + 2];
        }
        const float rx = px - q_lds[m][0];
        const float ry = py - q_lds[m][1];
        const float rz = pz - q_lds[m][2];
#pragma unroll
        for (int k = 0; k < KK; k++) {
            const float dx = rx - kp_lds[k][0];
            const float dy = ry - kp_lds[k][1];
            const float dz = rz - kp_lds[k][2];
            const float d2 = dx * dx + dy * dy + dz * dz;
            w_lds[m][k][h] = f2bf(fmaxf(1.0f - sqrtf(d2) * 0.5f, 0.0f));
        }
        w_lds[m][15][h] = 0;
    }

    // neighbor counts from precomputed row sums -> 1/cnt in LDS
#pragma unroll
    for (int s = 0; s < 2; s++) {
        const int it = s * 256 + t;
        const int m = it >> 5, h = it & 31;
        const int idx = idx_lds[m][h];
        const bool ok = (idx < NPTS) && (rowsum[idx] > 0.0f);
        const unsigned long long b = __ballot(ok);
        if (h == 0) {
            const unsigned half = (unsigned)(b >> ((m & 1) * 32));
            const int cnt = __popc(half);
            inv_lds[m] = 1.0f / (float)(cnt < 1 ? 1 : cnt);
        }
    }
    __syncthreads();   // ONLY barrier before waves go fully async

    // ---------------- wave-private m-loop (no barriers) ----------------
#pragma unroll 1
    for (int mi = 0; mi < 4; mi++) {
        const int m = wv * 4 + mi;

        // gather: 8 x dwordx4, rows paired so stage writes pack 2 h per b32
        float4 ga[8];
        const int rbase = lq * 2;
#pragma unroll
        for (int g2 = 0; g2 < 4; g2++) {
            const int r0 = g2 * 8 + rbase;
            const int i0 = idx_lds[m][r0];
            const int i1 = idx_lds[m][r0 + 1];
            ga[2 * g2]     = (i0 < NPTS) ? *(const float4*)&s_feats[i0 * 64 + l15 * 4]
                                         : make_float4(0.f, 0.f, 0.f, 0.f);
            ga[2 * g2 + 1] = (i1 < NPTS) ? *(const float4*)&s_feats[i1 * 64 + l15 * 4]
                                         : make_float4(0.f, 0.f, 0.f, 0.f);
        }

        // transpose-write: stage[wv][c=l15*4+i][r0], packed (r0, r0+1) per b32
#pragma unroll
        for (int g2 = 0; g2 < 4; g2++) {
            const int r0 = g2 * 8 + rbase;
            const float4 a = ga[2 * g2];
            const float4 b = ga[2 * g2 + 1];
            unsigned p0 = f2bf(a.x) | ((unsigned)f2bf(b.x) << 16);
            unsigned p1 = f2bf(a.y) | ((unsigned)f2bf(b.y) << 16);
            unsigned p2 = f2bf(a.z) | ((unsigned)f2bf(b.z) << 16);
            unsigned p3 = f2bf(a.w) | ((unsigned)f2bf(b.w) << 16);
            *(unsigned*)&stage[wv][l15 * 4 + 0][r0] = p0;
            *(unsigned*)&stage[wv][l15 * 4 + 1][r0] = p1;
            *(unsigned*)&stage[wv][l15 * 4 + 2][r0] = p2;
            *(unsigned*)&stage[wv][l15 * 4 + 3][r0] = p3;
        }

        // 4 MFMAs (c-tiles), scale by 1/cnt, store weighted row (512 B/wave, coalesced)
        const short8 afrag = lds_load8(&w_lds[m][l15][lq * 8]);
        const float inv = inv_lds[m];
        unsigned short* wrow = wt + (size_t)(lr0 + m) * KC;
#pragma unroll
        for (int ct = 0; ct < 4; ct++) {
            const short8 bfrag = lds_load8(&stage[wv][ct * 16 + l15][lq * 8]);
            floatx4 d = {0.f, 0.f, 0.f, 0.f};
            d = __builtin_amdgcn_mfma_f32_16x16x32_bf16(afrag, bfrag, d, 0, 0, 0);
            ushort4 pk;
            pk.x = f2bf(d[0] * inv);
            pk.y = f2bf(d[1] * inv);
            pk.z = f2bf(d[2] * inv);
            pk.w = f2bf(d[3] * inv);
            *(ushort4*)&wrow[(ct * 16 + l15) * 16 + lq * 4] = pk;
        }
    }
}

// =======================================================================
// K2: out[m][d] = sum_kc wt[m][kc] * W''[kc][d]  (wt already /cnt).
// Per wave: 16 rows x 64 d; A-frags b128 from ws (L3-hot), B-frags b128
// from wbf (L2-resident). 128 MFMAs/wave. LDS-free -> high occupancy.
// =======================================================================
__global__ __launch_bounds__(256) void k2_gemm(
    const unsigned short* __restrict__ wt,   // (chunk_rows, 1024)
    const unsigned short* __restrict__ wbf,  // (64, 1024)
    float* __restrict__ out,
    int base_row, int chunk_rows)
{
    const int t    = threadIdx.x;
    const int lane = t & 63;
    const int wv   = t >> 6;
    const int l15  = lane & 15;
    const int lq   = lane >> 4;
    const int lrow0 = blockIdx.x * 64 + wv * 16;
    if (lrow0 >= chunk_rows) return;

    const unsigned short* ap = wt + (size_t)(lrow0 + l15) * KC + lq * 8;
    const unsigned short* bp = wbf + lq * 8;

    floatx4 acc0 = {0.f, 0.f, 0.f, 0.f};
    floatx4 acc1 = {0.f, 0.f, 0.f, 0.f};
    floatx4 acc2 = {0.f, 0.f, 0.f, 0.f};
    floatx4 acc3 = {0.f, 0.f, 0.f, 0.f};

#pragma unroll 4
    for (int s = 0; s < KC / 32; s++) {
        const short8 a = *(const short8*)(ap + s * 32);
        const short8 b0 = *(const short8*)(bp + (0 * 16 + l15) * KC + s * 32);
        const short8 b1 = *(const short8*)(bp + (1 * 16 + l15) * KC + s * 32);
        const short8 b2 = *(const short8*)(bp + (2 * 16 + l15) * KC + s * 32);
        const short8 b3 = *(const short8*)(bp + (3 * 16 + l15) * KC + s * 32);
        acc0 = __builtin_amdgcn_mfma_f32_16x16x32_bf16(a, b0, acc0, 0, 0, 0);
        acc1 = __builtin_amdgcn_mfma_f32_16x16x32_bf16(a, b1, acc1, 0, 0, 0);
        acc2 = __builtin_amdgcn_mfma_f32_16x16x32_bf16(a, b2, acc2, 0, 0, 0);
        acc3 = __builtin_amdgcn_mfma_f32_16x16x32_bf16(a, b3, acc3, 0, 0, 0);
    }

    const int grow = base_row + lrow0 + lq * 4;   // D rows m = lq*4+r
#pragma unroll
    for (int r = 0; r < 4; r++) {
        float* orow = out + (size_t)(grow + r) * 64 + l15;
        orow[0]  = acc0[r];
        orow[16] = acc1[r];
        orow[32] = acc2[r];
        orow[48] = acc3[r];
    }
}

// =======================================================================
// Fallback (small ws): round-4 fused kernel, proven correct/passing.
// =======================================================================
#define F_TM 16
#define F_WTP 1032
#define F_WLP 40
#define F_FSP 66

__global__ __launch_bounds__(256, 2) void kpconv_fused(
    const float* __restrict__ q_points, const float* __restrict__ s_points,
    const float* __restrict__ s_feats, const int* __restrict__ nbr,
    const unsigned short* __restrict__ wbf, const float* __restrict__ kpts,
    const float* __restrict__ rowsum, float* __restrict__ out)
{
    const int t = threadIdx.x;
    const int m0 = blockIdx.x * F_TM;
    const int lane = t & 63;
    const int wv = t >> 6;
    const int l15 = lane & 15;
    const int lq = lane >> 4;

    __shared__ float q_lds[F_TM][3];
    __shared__ float kp_lds[KK][4];
    __shared__ int idx_lds[F_TM][HH];
    __shared__ __align__(16) unsigned short w_lds[F_TM][16][F_WLP];
    __shared__ __align__(16) float fstage[2][HH][F_FSP];
    __shared__ __align__(16) unsigned short wt_lds[F_TM][F_WTP];
    __shared__ float invcnt[F_TM];

    if (t < F_TM * 3) q_lds[t / 3][t % 3] = q_points[m0 * 3 + t];
    if (t < KK * 3) kp_lds[t / 3][t % 3] = kpts[t];
    idx_lds[t >> 5][t & 31] = nbr[m0 * HH + t];
    idx_lds[(t + 256) >> 5][t & 31] = nbr[m0 * HH + t + 256];
    __syncthreads();

    const int gh = t >> 4, gc4 = (t & 15) * 4;
    float4 g0, g1;
    {
        const int i0 = idx_lds[0][gh];
        const int i1 = idx_lds[0][gh + 16];
        g0 = (i0 < NPTS) ? *(const float4*)&s_feats[i0 * 64 + gc4] : make_float4(0.f, 0.f, 0.f, 0.f);
        g1 = (i1 < NPTS) ? *(const float4*)&s_feats[i1 * 64 + gc4] : make_float4(0.f, 0.f, 0.f, 0.f);
    }
#pragma unroll
    for (int s = 0; s < 2; s++) {
        const int it = s * 256 + t;
        const int m = it >> 5, h = it & 31;
        const int idx = idx_lds[m][h];
        float px = 1.0e6f, py = 1.0e6f, pz = 1.0e6f;
        if (idx < NPTS) {
            px = s_points[idx * 3 + 0]; py = s_points[idx * 3 + 1]; pz = s_points[idx * 3 + 2];
        }
        const float rx = px - q_lds[m][0], ry = py - q_lds[m][1], rz = pz - q_lds[m][2];
#pragma unroll
        for (int k = 0; k < KK; k++) {
            const float dx = rx - kp_lds[k][0], dy = ry - kp_lds[k][1], dz = rz - kp_lds[k][2];
            w_lds[m][k][h] = f2bf(fmaxf(1.0f - sqrtf(dx * dx + dy * dy + dz * dz) * 0.5f, 0.0f));
        }
        w_lds[m][15][h] = 0;
    }
#pragma unroll
    for (int s = 0; s < 2; s++) {
        const int it = s * 256 + t;
        const int m = it >> 5, h = it & 31;
        const int idx = idx_lds[m][h];
        const bool ok = (idx < NPTS) && (rowsum[idx] > 0.0f);
        const unsigned long long b = __ballot(ok);
        if (h == 0) {
            const unsigned half = (unsigned)(b >> ((m & 1) * 32));
            const int cnt = __popc(half);
            invcnt[m] = 1.0f / (float)(cnt < 1 ? 1 : cnt);
        }
    }
    {
        float* w0 = &fstage[0][gh][gc4];
        float* w1 = &fstage[0][gh + 16][gc4];
        *(float2*)(w0) = make_float2(g0.x, g0.y);
        *(float2*)(w0 + 2) = make_float2(g0.z, g0.w);
        *(float2*)(w1) = make_float2(g1.x, g1.y);
        *(float2*)(w1 + 2) = make_float2(g1.z, g1.w);
    }
    const int c = wv * 16 + l15;
#pragma unroll
    for (int m = 0; m < F_TM; m++) {
        __syncthreads();
        const int mb = m & 1;
        if (m < F_TM - 1) {
            const int i0 = idx_lds[m + 1][gh];
            const int i1 = idx_lds[m + 1][gh + 16];
            g0 = (i0 < NPTS) ? *(const float4*)&s_feats[i0 * 64 + gc4] : make_float4(0.f, 0.f, 0.f, 0.f);
            g1 = (i1 < NPTS) ? *(const float4*)&s_feats[i1 * 64 + gc4] : make_float4(0.f, 0.f, 0.f, 0.f);
        }
        const float* bp = &fstage[mb][lq * 8][c];
        short8 bfr;
#pragma unroll
        for (int j = 0; j < 8; j++) bfr[j] = (short)f2bf(bp[j * F_FSP]);
        const short8 a = lds_load8(&w_lds[m][l15][lq * 8]);
        floatx4 d = {0.f, 0.f, 0.f, 0.f};
        d = __builtin_amdgcn_mfma_f32_16x16x32_bf16(a, bfr, d, 0, 0, 0);
        ushort4 pk;
        pk.x = f2bf(d[0]); pk.y = f2bf(d[1]); pk.z = f2bf(d[2]); pk.w = f2bf(d[3]);
        *(ushort4*)&wt_lds[m][c * 16 + lq * 4] = pk;
        if (m < F_TM - 1) {
            float* w0 = &fstage[mb ^ 1][gh][gc4];
            float* w1 = &fstage[mb ^ 1][gh + 16][gc4];
            *(float2*)(w0) = make_float2(g0.x, g0.y);
            *(float2*)(w0 + 2) = make_float2(g0.z, g0.w);
            *(float2*)(w1) = make_float2(g1.x, g1.y);
            *(float2*)(w1 + 2) = make_float2(g1.z, g1.w);
        }
    }
    __syncthreads();
    {
        floatx4 acc = {0.f, 0.f, 0.f, 0.f};
        const unsigned short* apx = &wt_lds[l15][lq * 8];
        const unsigned short* bpx = wbf + (wv * 16 + l15) * KC + lq * 8;
#pragma unroll 8
        for (int s = 0; s < KC / 32; s++) {
            const short8 a = lds_load8(apx + s * 32);
            const short8 b = *(const short8*)(bpx + s * 32);
            acc = __builtin_amdgcn_mfma_f32_16x16x32_bf16(a, b, acc, 0, 0, 0);
        }
        const int d = wv * 16 + l15;
#pragma unroll
        for (int r = 0; r < 4; r++) {
            const int m = lq * 4 + r;
            out[(m0 + m) * 64 + d] = acc[r] * invcnt[m];
        }
    }
}

extern "C" void kernel_launch(void* const* d_in, const int* in_sizes, int n_in,
                              void* d_out, int out_size, void* d_ws, size_t ws_size,
                              hipStream_t stream) {
    const float* q_points = (const float*)d_in[0];
    const float* s_points = (const float*)d_in[1];
    const float* s_feats  = (const float*)d_in[2];
    const int*   nbr      = (const int*)d_in[3];
    const float* weights  = (const float*)d_in[4];
    const float* kpts     = (const float*)d_in[5];
    float* out = (float*)d_out;

    char* ws = (char*)d_ws;
    unsigned short* wbf = (unsigned short*)ws;            // 131072 B
    float* rowsum = (float*)(ws + 131072);                // 400000 B
    const size_t WT_OFF = 532480;                         // 16B-aligned, past wbf+rowsum

    prep_weights<<<64 * KC / 256, 256, 0, stream>>>(weights, wbf);
    prep_rowsum<<<(2 * NPTS + 255) / 256, 256, 0, stream>>>(s_feats, rowsum);

    long chunk = 0;
    if      (ws_size >= WT_OFF + 50000ull * 2048) chunk = 50000;
    else if (ws_size >= WT_OFF + 10000ull * 2048) chunk = 10000;
    else if (ws_size >= WT_OFF + 2000ull  * 2048) chunk = 2000;

    if (chunk) {
        unsigned short* wt = (unsigned short*)(ws + WT_OFF);
        for (int base = 0; base < MPTS; base += (int)chunk) {
            k1_weighted<<<(int)chunk / 16, 256, 0, stream>>>(
                q_points, s_points, s_feats, nbr, kpts, rowsum, wt, base);
            k2_gemm<<<((int)chunk + 63) / 64, 256, 0, stream>>>(
                wt, wbf, out, base, (int)chunk);
        }
    } else {
        kpconv_fused<<<MPTS / F_TM, 256, 0, stream>>>(
            q_points, s_points, s_feats, nbr, wbf, kpts, rowsum, out);
    }
}

// Round 6
// 202.311 us; speedup vs baseline: 1.2331x; 1.2331x over previous
//
#include <hip/hip_runtime.h>
#include <hip/hip_bf16.h>

#define MPTS 50000
#define NPTS 100000
#define HH 32
#define KK 15
#define KC 1024        // phase-C K dim: 64 c * 16 k (k=15 zero pad)
#define WTP 1032       // overlay row stride (shorts): w[16][36] early, weighted[1024] late
#define STP 36         // stage stride (shorts): b64 reads aligned + conflict-free

typedef __attribute__((ext_vector_type(8))) short short8;
typedef __attribute__((ext_vector_type(4))) short short4v;
typedef __attribute__((ext_vector_type(4))) float floatx4;

static __device__ __forceinline__ unsigned short f2bf(float f) {
    __hip_bfloat16 h = __float2bfloat16(f);
    return *reinterpret_cast<unsigned short*>(&h);
}

static __device__ __forceinline__ short8 lds_load8(const unsigned short* p) {
    const short4v a = *(const short4v*)p;
    const short4v b = *(const short4v*)(p + 4);
    short8 r;
    r[0] = a[0]; r[1] = a[1]; r[2] = a[2]; r[3] = a[3];
    r[4] = b[0]; r[5] = b[1]; r[6] = b[2]; r[7] = b[3];
    return r;
}

// ---- prep 1: W''[d][c*16+k] = bf16(weights[k][c][d]), k=15 row zeroed (128 KB)
__global__ void prep_weights(const float* __restrict__ w, unsigned short* __restrict__ wbf) {
    const int i = blockIdx.x * 256 + threadIdx.x;       // 65536
    const int d = i >> 10, kc = i & (KC - 1);
    const int c = kc >> 4, k = kc & 15;
    const float v = (k < KK) ? w[k * 4096 + c * 64 + d] : 0.0f;
    wbf[i] = f2bf(v);
}

// ---- prep 2: exact numpy-pairwise-order row sums of s_feats (400 KB)
__global__ void prep_rowsum(const float* __restrict__ sf, float* __restrict__ rs) {
    const int t = blockIdx.x * 256 + threadIdx.x;
    const int row = t >> 1, p = t & 1;
    if (row >= NPTS) return;
    const float* base = sf + row * 64 + p * 4;
    float4 r = *(const float4*)base;
#pragma unroll
    for (int i = 1; i < 8; i++) {
        const float4 x = *(const float4*)(base + i * 8);
        r.x += x.x; r.y += x.y; r.z += x.z; r.w += x.w;
    }
    float sp = (r.x + r.y) + (r.z + r.w);
    sp += __shfl_xor(sp, 1);
    if (p == 0) rs[row] = sp;
}

// ---- prep 3: s_feats fp32 -> bf16 (12.8 MB), halves gather traffic
__global__ void prep_sfb(const float* __restrict__ sf, unsigned short* __restrict__ sfb) {
    const int i = blockIdx.x * 256 + threadIdx.x;       // N*16 quads
    if (i >= NPTS * 16) return;
    const float4 v = *(const float4*)(sf + (size_t)i * 4);
    ushort4 o;
    o.x = f2bf(v.x); o.y = f2bf(v.y); o.z = f2bf(v.z); o.w = f2bf(v.w);
    *(ushort4*)(sfb + (size_t)i * 4) = o;
}

// =======================================================================
// Fused kernel. LDS: idx 2048 + q 192 + kp 240 + inv 64 + stage 18432 +
// overlay wtw 33024 = 54000 B -> 3 blocks/CU (12 waves).
// Structure: phase A (coop loads, barrier) -> per-wave w/cnt compute ->
// barrier-free m-loop (gather prefetch, stage transpose, MFMA-B, weighted
// row overlays its own w region) -> barrier -> MFMA phase C.
// =======================================================================
__global__ __launch_bounds__(256, 3) void kpconv_fused(
    const float* __restrict__ q_points,      // (M,3)
    const float* __restrict__ s_points,      // (N,3)
    const unsigned short* __restrict__ sfb,  // (N,64) bf16
    const int*   __restrict__ nbr,           // (M,32)
    const unsigned short* __restrict__ wbf,  // (64,1024) bf16
    const float* __restrict__ kpts,          // (15,3)
    const float* __restrict__ rowsum,        // (N,)
    float* __restrict__ out)                 // (M,64)
{
    const int t    = threadIdx.x;
    const int m0   = blockIdx.x * 16;
    const int lane = t & 63;
    const int wv   = t >> 6;
    const int l15  = lane & 15;
    const int lq   = lane >> 4;

    __shared__ int   idx_lds[16][HH];
    __shared__ float q_lds[16][3];
    __shared__ float kp_lds[KK][4];
    __shared__ float inv_lds[16];
    __shared__ unsigned short stage[4][64 * STP];    // per-wave [c][h-packed], 18432 B
    __shared__ unsigned short wtw[16 * WTP];         // overlay: w[m][k][h] then weighted[m][kc]

    // ---------------- Phase A: cooperative small loads ----------------
    if (t < 16 * 3) q_lds[t / 3][t % 3] = q_points[m0 * 3 + t];
    if (t < KK * 3) kp_lds[t / 3][t % 3] = kpts[t];
    idx_lds[t >> 5][t & 31]         = nbr[m0 * HH + t];
    idx_lds[(t + 256) >> 5][t & 31] = nbr[m0 * HH + t + 256];
    __syncthreads();   // barrier 1 of 2

    // -------- per-wave: kernel-point weights into overlay region + counts --------
#pragma unroll
    for (int s = 0; s < 2; s++) {
        const int m = wv * 4 + s * 2 + (lane >> 5);
        const int h = lane & 31;
        const int idx = idx_lds[m][h];
        float px = 1.0e6f, py = 1.0e6f, pz = 1.0e6f;
        if (idx < NPTS) {
            px = s_points[idx * 3 + 0];
            py = s_points[idx * 3 + 1];
            pz = s_points[idx * 3 + 2];
        }
        const float rx = px - q_lds[m][0];
        const float ry = py - q_lds[m][1];
        const float rz = pz - q_lds[m][2];
        unsigned short* wrow = &wtw[m * WTP];
#pragma unroll
        for (int k = 0; k < KK; k++) {
            const float dx = rx - kp_lds[k][0];
            const float dy = ry - kp_lds[k][1];
            const float dz = rz - kp_lds[k][2];
            const float d2 = dx * dx + dy * dy + dz * dz;
            wrow[k * STP + h] = f2bf(fmaxf(1.0f - sqrtf(d2) * 0.5f, 0.0f));
        }
        wrow[15 * STP + h] = 0;   // k-pad row

        // neighbor count (per-m ballot half, exact: sum>0 on precomputed numpy-order sums)
        const bool ok = (idx < NPTS) && (rowsum[idx] > 0.0f);
        const unsigned long long b = __ballot(ok);
        if (h == 0) {
            const unsigned half = (unsigned)(b >> ((lane >> 5) * 32));
            const int cnt = __popc(half);
            inv_lds[m] = 1.0f / (float)(cnt < 1 ? 1 : cnt);
        }
    }

    // ---------------- barrier-free m-loop (wave-private, prefetched) ----------------
    unsigned short* const st = stage[wv];
    const int c4 = l15 * 4;

    ushort4 ga[8], gb[8];
    // prologue gather: mi=0 (rows paired 2-per-lane-slot; 16 lanes x 8 B = 128 B/row-pair instr)
#pragma unroll
    for (int g2 = 0; g2 < 4; g2++) {
        const int r0 = g2 * 8 + lq * 2;
        const int i0 = idx_lds[wv * 4][r0];
        const int i1 = idx_lds[wv * 4][r0 + 1];
        ga[2 * g2]     = (i0 < NPTS) ? *(const ushort4*)&sfb[(size_t)i0 * 64 + c4]
                                     : make_ushort4(0, 0, 0, 0);
        ga[2 * g2 + 1] = (i1 < NPTS) ? *(const ushort4*)&sfb[(size_t)i1 * 64 + c4]
                                     : make_ushort4(0, 0, 0, 0);
    }

#pragma unroll
    for (int mi = 0; mi < 4; mi++) {
        const int m = wv * 4 + mi;

        // prefetch mi+1 gather
        if (mi < 3) {
#pragma unroll
            for (int g2 = 0; g2 < 4; g2++) {
                const int r0 = g2 * 8 + lq * 2;
                const int i0 = idx_lds[m + 1][r0];
                const int i1 = idx_lds[m + 1][r0 + 1];
                gb[2 * g2]     = (i0 < NPTS) ? *(const ushort4*)&sfb[(size_t)i0 * 64 + c4]
                                             : make_ushort4(0, 0, 0, 0);
                gb[2 * g2 + 1] = (i1 < NPTS) ? *(const ushort4*)&sfb[(size_t)i1 * 64 + c4]
                                             : make_ushort4(0, 0, 0, 0);
            }
        }

        // transpose-write to private stage: [c][h] bf16, rows packed 2-per-b32
#pragma unroll
        for (int g2 = 0; g2 < 4; g2++) {
            const int r0 = g2 * 8 + lq * 2;
            const ushort4 a = ga[2 * g2];
            const ushort4 b = ga[2 * g2 + 1];
            *(unsigned*)&st[(c4 + 0) * STP + r0] = (unsigned)a.x | ((unsigned)b.x << 16);
            *(unsigned*)&st[(c4 + 1) * STP + r0] = (unsigned)a.y | ((unsigned)b.y << 16);
            *(unsigned*)&st[(c4 + 2) * STP + r0] = (unsigned)a.z | ((unsigned)b.z << 16);
            *(unsigned*)&st[(c4 + 3) * STP + r0] = (unsigned)a.w | ((unsigned)b.w << 16);
        }

        // A-frag from overlay w region (read BEFORE this row is overwritten below)
        const short8 afrag = lds_load8(&wtw[m * WTP + l15 * STP + lq * 8]);
        const float inv = inv_lds[m];

        // 4 c-tile MFMAs; weighted row (pre-scaled, bf16) overlays w[m]
#pragma unroll
        for (int ct = 0; ct < 4; ct++) {
            const short8 bfrag = lds_load8(&st[(ct * 16 + l15) * STP + lq * 8]);
            floatx4 d = {0.f, 0.f, 0.f, 0.f};
            d = __builtin_amdgcn_mfma_f32_16x16x32_bf16(afrag, bfrag, d, 0, 0, 0);
            ushort4 pk;
            pk.x = f2bf(d[0] * inv);
            pk.y = f2bf(d[1] * inv);
            pk.z = f2bf(d[2] * inv);
            pk.w = f2bf(d[3] * inv);
            *(ushort4*)&wtw[m * WTP + (ct * 16 + l15) * 16 + lq * 4] = pk;
        }

#pragma unroll
        for (int j = 0; j < 8; j++) ga[j] = gb[j];
    }
    __syncthreads();   // barrier 2 of 2: all weighted rows + inv visible

    // ---------------- Phase C: out[m][d] = sum_kc weighted[m][kc] * W''[kc][d] ----------------
    {
        floatx4 acc = {0.f, 0.f, 0.f, 0.f};
        const unsigned short* ap = &wtw[l15 * WTP + lq * 8];
        const unsigned short* bp = wbf + (wv * 16 + l15) * KC + lq * 8;
#pragma unroll 8
        for (int s = 0; s < KC / 32; s++) {
            const short8 a = lds_load8(ap + s * 32);
            const short8 b = *(const short8*)(bp + s * 32);
            acc = __builtin_amdgcn_mfma_f32_16x16x32_bf16(a, b, acc, 0, 0, 0);
        }
        const int d = wv * 16 + l15;
#pragma unroll
        for (int r = 0; r < 4; r++)
            out[(size_t)(m0 + lq * 4 + r) * 64 + d] = acc[r];
    }
}

extern "C" void kernel_launch(void* const* d_in, const int* in_sizes, int n_in,
                              void* d_out, int out_size, void* d_ws, size_t ws_size,
                              hipStream_t stream) {
    const float* q_points = (const float*)d_in[0];
    const float* s_points = (const float*)d_in[1];
    const float* s_feats  = (const float*)d_in[2];
    const int*   nbr      = (const int*)d_in[3];
    const float* weights  = (const float*)d_in[4];
    const float* kpts     = (const float*)d_in[5];
    float* out = (float*)d_out;

    char* ws = (char*)d_ws;
    unsigned short* wbf = (unsigned short*)ws;               // 131072 B
    float* rowsum = (float*)(ws + 131072);                   // 400000 B
    unsigned short* sfb = (unsigned short*)(ws + 532480);    // 12.8 MB bf16 feats

    prep_weights<<<64 * KC / 256, 256, 0, stream>>>(weights, wbf);
    prep_rowsum<<<(2 * NPTS + 255) / 256, 256, 0, stream>>>(s_feats, rowsum);
    prep_sfb<<<(NPTS * 16 + 255) / 256, 256, 0, stream>>>(s_feats, sfb);

    kpconv_fused<<<MPTS / 16, 256, 0, stream>>>(q_points, s_points, sfb, nbr,
                                                wbf, kpts, rowsum, out);
}

// Round 7
// 150.504 us; speedup vs baseline: 1.6576x; 1.3442x over previous
//
#include <hip/hip_runtime.h>
#include <hip/hip_bf16.h>

#define MPTS 50000
#define NPTS 100000
#define KK 15
#define KC 1024
#define WTP 1036   // wtw row stride (shorts): 518 b32 = 6 mod 32 -> phase-C A reads 2-way (free)
#define STP 36     // stage row stride (shorts)

typedef __attribute__((ext_vector_type(8))) short short8;
typedef __attribute__((ext_vector_type(4))) short short4v;
typedef __attribute__((ext_vector_type(4))) float floatx4;

static __device__ __forceinline__ unsigned short f2bf(float f) {
    __hip_bfloat16 h = __float2bfloat16(f);
    return *reinterpret_cast<unsigned short*>(&h);
}

static __device__ __forceinline__ short8 lds_load8(const unsigned short* p) {
    const short4v a = *(const short4v*)p;
    const short4v b = *(const short4v*)(p + 4);
    short8 r;
    r[0] = a[0]; r[1] = a[1]; r[2] = a[2]; r[3] = a[3];
    r[4] = b[0]; r[5] = b[1]; r[6] = b[2]; r[7] = b[3];
    return r;
}

// ===================== single merged prep kernel (3 jobs by blockIdx range) ==================
// blocks [0,6250): s_feats fp32 -> bf16 (12.8 MB)
// blocks [6250,7032): exact numpy-pairwise-order row sums (400 KB)
// blocks [7032,7064): wbf2 lane-linear B fragments: entry e=(wq*32+s)*64+lane holds 8 bf16 of
//                     W''[d=wq*16+(lane&15)][kc=s*32+(lane>>4)*8+j], k=15 zeroed (128 KB)
__global__ void prep_all(const float* __restrict__ sf, const float* __restrict__ w,
                         unsigned short* __restrict__ sfb, float* __restrict__ rs,
                         unsigned short* __restrict__ wbf2) {
    const int b = blockIdx.x, t = threadIdx.x;
    if (b < 6250) {
        const int i = b * 256 + t;                     // quad index < NPTS*16
        const float4 v = *(const float4*)(sf + (size_t)i * 4);
        ushort4 o;
        o.x = f2bf(v.x); o.y = f2bf(v.y); o.z = f2bf(v.z); o.w = f2bf(v.w);
        *(ushort4*)(sfb + (size_t)i * 4) = o;
    } else if (b < 7032) {
        const int tt = (b - 6250) * 256 + t;
        const int row = tt >> 1, p = tt & 1;
        if (row < NPTS) {
            const float* base = sf + (size_t)row * 64 + p * 4;
            float4 r = *(const float4*)base;
#pragma unroll
            for (int i = 1; i < 8; i++) {
                const float4 x = *(const float4*)(base + i * 8);
                r.x += x.x; r.y += x.y; r.z += x.z; r.w += x.w;
            }
            float sp = (r.x + r.y) + (r.z + r.w);
            sp += __shfl_xor(sp, 1);
            if (p == 0) rs[row] = sp;
        }
    } else {
        const int e = (b - 7032) * 256 + t;            // 0..8191
        const int lane = e & 63, s = (e >> 6) & 31, wq = e >> 11;
        const int d = wq * 16 + (lane & 15);
        const int lqp = lane >> 4;
        unsigned short o8[8];
#pragma unroll
        for (int j = 0; j < 8; j++) {
            const int kc = s * 32 + lqp * 8 + j;
            const int c = kc >> 4, k = kc & 15;
            o8[j] = (k < KK) ? f2bf(w[k * 4096 + c * 64 + d]) : (unsigned short)0;
        }
#pragma unroll
        for (int j = 0; j < 8; j++) wbf2[(size_t)e * 8 + j] = o8[j];
    }
}

// =======================================================================
// Fused main kernel. LDS: idx 2048 + stage 18432 + wtw 33152 = 53632 B
// -> 3 blocks/CU. ONE __syncthreads in the whole kernel (pre phase C).
// Wave-private m-loop, 4-deep gather prefetch, swizzled conflict-free LDS.
// =======================================================================
__global__ __launch_bounds__(256, 3) void kpconv_fused(
    const float* __restrict__ q_points,
    const float* __restrict__ s_points,
    const unsigned short* __restrict__ sfb,   // (N,64) bf16
    const int*   __restrict__ nbr,            // (M,32)
    const unsigned short* __restrict__ wbf2,  // lane-linear B frags (128 KB)
    const float* __restrict__ kpts,           // (15,3)
    const float* __restrict__ rowsum,         // (N,)
    float* __restrict__ out)                  // (M,64)
{
    const int t    = threadIdx.x;
    const int m0   = blockIdx.x * 16;
    const int lane = t & 63;
    const int wv   = t >> 6;
    const int l15  = lane & 15;
    const int lq   = lane >> 4;

    __shared__ int idx_lds[16][32];
    __shared__ unsigned short stage[4][64 * STP];   // per-wave [c][h-swizzled]
    __shared__ unsigned short wtw[16 * WTP];        // w[k][h] early, weighted[kc] late

    // per-wave idx load (wave-local; same-wave LDS ordering, no barrier needed)
    {
        const int r = 4 * wv + lq;
        const int2 iv = *(const int2*)&nbr[(size_t)(m0 + r) * 32 + l15 * 2];
        *(int2*)&idx_lds[r][l15 * 2] = iv;
    }

    // ---- issue ALL 4 m gathers (32 x 8B, rows paired per lane slot) ----
    ushort4 g[4][8];
    const int c4 = l15 * 4;
#pragma unroll
    for (int mi = 0; mi < 4; mi++) {
        const int m = 4 * wv + mi;
#pragma unroll
        for (int g2 = 0; g2 < 4; g2++) {
            const int r0 = g2 * 8 + lq * 2;
            const int2 ip = *(const int2*)&idx_lds[m][r0];
            g[mi][2 * g2]     = (ip.x < NPTS) ? *(const ushort4*)&sfb[(size_t)ip.x * 64 + c4]
                                              : make_ushort4(0, 0, 0, 0);
            g[mi][2 * g2 + 1] = (ip.y < NPTS) ? *(const ushort4*)&sfb[(size_t)ip.y * 64 + c4]
                                              : make_ushort4(0, 0, 0, 0);
        }
    }

    // ---- kernel-point weights + counts (VALU work covers gather latency) ----
    float inv[4];
#pragma unroll
    for (int s = 0; s < 2; s++) {
        const int m = 4 * wv + 2 * s + (lane >> 5);
        const int h = lane & 31;
        const int idx = idx_lds[m][h];
        float px = 1.0e6f, py = 1.0e6f, pz = 1.0e6f;
        if (idx < NPTS) {
            px = s_points[idx * 3 + 0];
            py = s_points[idx * 3 + 1];
            pz = s_points[idx * 3 + 2];
        }
        const float rx = px - q_points[(m0 + m) * 3 + 0];
        const float ry = py - q_points[(m0 + m) * 3 + 1];
        const float rz = pz - q_points[(m0 + m) * 3 + 2];
        unsigned short* wrow = &wtw[m * WTP];
#pragma unroll
        for (int k = 0; k < KK; k++) {
            const float dx = rx - kpts[k * 3 + 0];   // uniform addr -> s_load, L2-hot
            const float dy = ry - kpts[k * 3 + 1];
            const float dz = rz - kpts[k * 3 + 2];
            const float d2 = dx * dx + dy * dy + dz * dz;
            wrow[k * STP + h] = f2bf(fmaxf(1.0f - sqrtf(d2) * 0.5f, 0.0f));
        }
        wrow[15 * STP + h] = 0;                      // k-pad row

        const bool ok = (idx < NPTS) && (rowsum[idx] > 0.0f);
        const unsigned long long bal = __ballot(ok);
        const int cLo = __popc((unsigned)bal);
        const int cHi = __popc((unsigned)(bal >> 32));
        inv[2 * s + 0] = 1.0f / (float)(cLo < 1 ? 1 : cLo);
        inv[2 * s + 1] = 1.0f / (float)(cHi < 1 ? 1 : cHi);
    }

    // ---- wave-private m-loop (no barriers; swizzled stage) ----
    unsigned short* const st = stage[wv];
    const int swzw = (l15 >> 2) << 2;                // write key = (c>>4)&3 for c=4*l15+i
#pragma unroll
    for (int mi = 0; mi < 4; mi++) {
        const int m = 4 * wv + mi;

        // transpose-write: b32 slot (g2*4+lq) ^ swz, rows c4..c4+3  -> 2-way banks (free)
#pragma unroll
        for (int g2 = 0; g2 < 4; g2++) {
            const int so = (((g2 * 4 + lq) ^ swzw)) * 2;   // shorts offset within row
            const ushort4 a = g[mi][2 * g2];
            const ushort4 b = g[mi][2 * g2 + 1];
            *(unsigned*)&st[(c4 + 0) * STP + so] = (unsigned)a.x | ((unsigned)b.x << 16);
            *(unsigned*)&st[(c4 + 1) * STP + so] = (unsigned)a.y | ((unsigned)b.y << 16);
            *(unsigned*)&st[(c4 + 2) * STP + so] = (unsigned)a.z | ((unsigned)b.z << 16);
            *(unsigned*)&st[(c4 + 3) * STP + so] = (unsigned)a.w | ((unsigned)b.w << 16);
        }

        const short8 afrag = lds_load8(&wtw[m * WTP + l15 * STP + lq * 8]);
        const float iv = inv[mi];
#pragma unroll
        for (int ct = 0; ct < 4; ct++) {
            // read key = (c>>4)&3 = ct -> slots ((lq^ct)*4 + u): contiguous, 2 aligned b64
            const short8 bfrag = lds_load8(&st[(ct * 16 + l15) * STP + ((lq ^ ct) * 8)]);
            floatx4 d = {0.f, 0.f, 0.f, 0.f};
            d = __builtin_amdgcn_mfma_f32_16x16x32_bf16(afrag, bfrag, d, 0, 0, 0);
            ushort4 pk;
            pk.x = f2bf(d[0] * iv);
            pk.y = f2bf(d[1] * iv);
            pk.z = f2bf(d[2] * iv);
            pk.w = f2bf(d[3] * iv);
            *(ushort4*)&wtw[m * WTP + (ct * 16 + l15) * 16 + lq * 4] = pk;
        }
    }
    __syncthreads();   // the ONLY barrier: all weighted rows visible

    // ---- Phase C: out[m][d] = sum_kc weighted[m][kc] * W''[kc][d] ----
    {
        floatx4 acc = {0.f, 0.f, 0.f, 0.f};
        const unsigned short* ap = &wtw[l15 * WTP + lq * 8];
        const unsigned short* bp = wbf2 + ((size_t)(wv * 32) * 64 + lane) * 8;
#pragma unroll 8
        for (int s = 0; s < 32; s++) {
            const short8 a = lds_load8(ap + s * 32);
            const short8 b = *(const short8*)(bp + s * 512);   // coalesced 1 KB/wave, L2-hot
            acc = __builtin_amdgcn_mfma_f32_16x16x32_bf16(a, b, acc, 0, 0, 0);
        }
        const int d = wv * 16 + l15;
#pragma unroll
        for (int r = 0; r < 4; r++)
            out[(size_t)(m0 + lq * 4 + r) * 64 + d] = acc[r];
    }
}

extern "C" void kernel_launch(void* const* d_in, const int* in_sizes, int n_in,
                              void* d_out, int out_size, void* d_ws, size_t ws_size,
                              hipStream_t stream) {
    const float* q_points = (const float*)d_in[0];
    const float* s_points = (const float*)d_in[1];
    const float* s_feats  = (const float*)d_in[2];
    const int*   nbr      = (const int*)d_in[3];
    const float* weights  = (const float*)d_in[4];
    const float* kpts     = (const float*)d_in[5];
    float* out = (float*)d_out;

    char* ws = (char*)d_ws;
    unsigned short* wbf2 = (unsigned short*)ws;              // 131072 B
    float* rowsum = (float*)(ws + 131072);                   // 400000 B
    unsigned short* sfb = (unsigned short*)(ws + 532480);    // 12.8 MB

    prep_all<<<7064, 256, 0, stream>>>(s_feats, weights, sfb, rowsum, wbf2);
    kpconv_fused<<<MPTS / 16, 256, 0, stream>>>(q_points, s_points, sfb, nbr,
                                                wbf2, kpts, rowsum, out);
}

// Round 8
// 149.184 us; speedup vs baseline: 1.6723x; 1.0088x over previous
//
#include <hip/hip_runtime.h>
#include <hip/hip_bf16.h>

#define MPTS 50000
#define NPTS 100000
#define KK 15
#define TM 8       // queries per block; wave owns 2 -> barrier-free m-loop, 4 blocks/CU
#define WTP 1036   // wtw row stride (shorts): 518 b32 = 6 mod 32 -> phase-C A reads uniform banks
#define STP 36     // stage row stride (shorts): 18 b32 -> all stage ops <=2-way

typedef __attribute__((ext_vector_type(8))) short short8;
typedef __attribute__((ext_vector_type(4))) short short4v;
typedef __attribute__((ext_vector_type(4))) float floatx4;

static __device__ __forceinline__ unsigned short f2bf(float f) {
    __hip_bfloat16 h = __float2bfloat16(f);
    return *reinterpret_cast<unsigned short*>(&h);
}

static __device__ __forceinline__ short8 lds_load8(const unsigned short* p) {
    const short4v a = *(const short4v*)p;
    const short4v b = *(const short4v*)(p + 4);
    short8 r;
    r[0] = a[0]; r[1] = a[1]; r[2] = a[2]; r[3] = a[3];
    r[4] = b[0]; r[5] = b[1]; r[6] = b[2]; r[7] = b[3];
    return r;
}

// ===================== single prep kernel (3 jobs by blockIdx range) ==================
// [0,782):   one pass over s_feats rows -> sfb (bf16) AND rowsum (exact numpy pairwise order)
// [782,814): wbf2 lane-linear B frags: e=(wq*32+s)*64+lane holds 8 bf16 of
//            W''[d=wq*16+(lane&15)][kc=s*32+(lane>>4)*8+j], k=15 zeroed (128 KB)
// 814:       tail: zero sfb row N, rowsum[N]=-1, kpp[k]={-2kx,-2ky,-2kz,|kp|^2}
__global__ void prep_all(const float* __restrict__ sf, const float* __restrict__ w,
                         const float* __restrict__ kpts,
                         unsigned short* __restrict__ sfb, float* __restrict__ rs,
                         unsigned short* __restrict__ wbf2, float4* __restrict__ kpp) {
    const int b = blockIdx.x, t = threadIdx.x;
    if (b < 782) {
        const int tt = b * 256 + t;
        const int row = tt >> 1, p = tt & 1;          // lane p covers cols 4p+8i+0..3
        if (row < NPTS) {
            const float* base = sf + (size_t)row * 64 + p * 4;
            float4 r = *(const float4*)base;          // i = 0
            {
                ushort4 o;
                o.x = f2bf(r.x); o.y = f2bf(r.y); o.z = f2bf(r.z); o.w = f2bf(r.w);
                *(ushort4*)&sfb[(size_t)row * 64 + p * 4] = o;
            }
#pragma unroll
            for (int i = 1; i < 8; i++) {
                const float4 x = *(const float4*)(base + i * 8);
                ushort4 o;
                o.x = f2bf(x.x); o.y = f2bf(x.y); o.z = f2bf(x.z); o.w = f2bf(x.w);
                *(ushort4*)&sfb[(size_t)row * 64 + i * 8 + p * 4] = o;
                r.x += x.x; r.y += x.y; r.z += x.z; r.w += x.w;   // strict per-j fold
            }
            float sp = (r.x + r.y) + (r.z + r.w);
            sp += __shfl_xor(sp, 1);                  // + other half (commutative: exact)
            if (p == 0) rs[row] = sp;
        }
    } else if (b < 814) {
        const int e = (b - 782) * 256 + t;            // 0..8191
        const int lane = e & 63, s = (e >> 6) & 31, wq = e >> 11;
        const int d = wq * 16 + (lane & 15);
        const int lqp = lane >> 4;
        unsigned short o8[8];
#pragma unroll
        for (int j = 0; j < 8; j++) {
            const int kc = s * 32 + lqp * 8 + j;
            const int c = kc >> 4, k = kc & 15;
            o8[j] = (k < KK) ? f2bf(w[k * 4096 + c * 64 + d]) : (unsigned short)0;
        }
#pragma unroll
        for (int j = 0; j < 8; j++) wbf2[(size_t)e * 8 + j] = o8[j];
    } else {
        if (t < 16) *(ushort4*)&sfb[(size_t)NPTS * 64 + t * 4] = make_ushort4(0, 0, 0, 0);
        else if (t == 16) rs[NPTS] = -1.0f;
        else if (t >= 32 && t < 32 + KK) {
            const int k = t - 32;
            const float kx = kpts[k * 3 + 0], ky = kpts[k * 3 + 1], kz = kpts[k * 3 + 2];
            kpp[k] = make_float4(-2.f * kx, -2.f * ky, -2.f * kz, kx * kx + ky * ky + kz * kz);
        }
    }
}

// =======================================================================
// Fused main kernel, TM=8. LDS: idx 1024 + stage 18432 + wtw 16576 + inv 32
// = 36064 B -> 4 blocks/CU (16 waves). ONE __syncthreads total.
// =======================================================================
__global__ __launch_bounds__(256, 4) void kpconv_fused(
    const float* __restrict__ q_points,
    const float* __restrict__ s_points,
    const unsigned short* __restrict__ sfb,   // (N+1,64) bf16, row N zero
    const int*   __restrict__ nbr,            // (M,32)
    const unsigned short* __restrict__ wbf2,  // lane-linear B frags (128 KB)
    const float4* __restrict__ kpp,           // (15) {-2kx,-2ky,-2kz,|kp|^2}
    const float* __restrict__ rowsum,         // (N+1), entry N = -1
    float* __restrict__ out)                  // (M,64)
{
    const int t    = threadIdx.x;
    const int m0   = blockIdx.x * TM;
    const int lane = t & 63;
    const int wv   = t >> 6;
    const int l15  = lane & 15;
    const int lq   = lane >> 4;

    __shared__ int idx_lds[TM][32];
    __shared__ unsigned short stage[4][64 * STP];   // per-wave [c][h-swizzled]
    __shared__ unsigned short wtw[TM * WTP];        // w[k][h] early, weighted[kc] late
    __shared__ float inv_lds[TM];

    // per-wave idx load (wave-local ordering; no barrier needed)
    const int mw = 2 * wv + (lane >> 5);
    const int h  = lane & 31;
    idx_lds[mw][h] = nbr[(size_t)(m0 + mw) * 32 + h];

    // ---- issue BOTH m gathers (16 x 8B, rows paired per lane slot; pad row = zeros) ----
    ushort4 g[2][8];
    const int c4 = l15 * 4;
#pragma unroll
    for (int mi = 0; mi < 2; mi++) {
        const int m = 2 * wv + mi;
#pragma unroll
        for (int g2 = 0; g2 < 4; g2++) {
            const int r0 = g2 * 8 + lq * 2;
            const int2 ip = *(const int2*)&idx_lds[m][r0];
            const int i0 = min(ip.x, NPTS);
            const int i1 = min(ip.y, NPTS);
            g[mi][2 * g2]     = *(const ushort4*)&sfb[(size_t)i0 * 64 + c4];
            g[mi][2 * g2 + 1] = *(const ushort4*)&sfb[(size_t)i1 * 64 + c4];
        }
    }

    // ---- kernel-point weights + counts (covers gather latency) ----
    {
        const int idx = idx_lds[mw][h];
        float px = 1.0e6f, py = 1.0e6f, pz = 1.0e6f;
        if (idx < NPTS) {
            px = s_points[idx * 3 + 0];
            py = s_points[idx * 3 + 1];
            pz = s_points[idx * 3 + 2];
        }
        const float rx = px - q_points[(m0 + mw) * 3 + 0];
        const float ry = py - q_points[(m0 + mw) * 3 + 1];
        const float rz = pz - q_points[(m0 + mw) * 3 + 2];
        const float r2 = rx * rx + ry * ry + rz * rz;
        unsigned short* wrow = &wtw[mw * WTP];
#pragma unroll
        for (int k = 0; k < KK; k++) {
            const float4 kp = kpp[k];                 // wave-uniform -> s_load
            float d2 = kp.w;
            d2 = fmaf(rx, kp.x, d2);
            d2 = fmaf(ry, kp.y, d2);
            d2 = fmaf(rz, kp.z, d2);
            d2 = fmaxf(r2 + d2, 0.0f);                // guard tiny-negative from rounding
            const float wv_ = fmaxf(fmaf(-0.5f, __builtin_amdgcn_sqrtf(d2), 1.0f), 0.0f);
            wrow[k * STP + h] = f2bf(wv_);
        }
        wrow[15 * STP + h] = 0;                       // k-pad row

        const bool ok = rowsum[min(idx, NPTS)] > 0.0f;   // rowsum[N] = -1
        const unsigned long long bal = __ballot(ok);
        if (h == 0) {
            const int cnt = __popc((unsigned)(bal >> ((lane >> 5) * 32)));
            inv_lds[mw] = 1.0f / (float)(cnt < 1 ? 1 : cnt);
        }
    }

    // ---- wave-private m-loop (no barriers; swizzled stage) ----
    unsigned short* const st = stage[wv];
    const int swzw = (l15 >> 2) << 2;
#pragma unroll
    for (int mi = 0; mi < 2; mi++) {
        const int m = 2 * wv + mi;

        // transpose-write: b32 slot (g2*4+lq)^swz -> <=2-way banks
#pragma unroll
        for (int g2 = 0; g2 < 4; g2++) {
            const int so = ((g2 * 4 + lq) ^ swzw) * 2;
            const ushort4 a = g[mi][2 * g2];
            const ushort4 b = g[mi][2 * g2 + 1];
            *(unsigned*)&st[(c4 + 0) * STP + so] = (unsigned)a.x | ((unsigned)b.x << 16);
            *(unsigned*)&st[(c4 + 1) * STP + so] = (unsigned)a.y | ((unsigned)b.y << 16);
            *(unsigned*)&st[(c4 + 2) * STP + so] = (unsigned)a.z | ((unsigned)b.z << 16);
            *(unsigned*)&st[(c4 + 3) * STP + so] = (unsigned)a.w | ((unsigned)b.w << 16);
        }

        const short8 afrag = lds_load8(&wtw[m * WTP + l15 * STP + lq * 8]);
#pragma unroll
        for (int ct = 0; ct < 4; ct++) {
            const short8 bfrag = lds_load8(&st[(ct * 16 + l15) * STP + ((lq ^ ct) * 8)]);
            floatx4 d = {0.f, 0.f, 0.f, 0.f};
            d = __builtin_amdgcn_mfma_f32_16x16x32_bf16(afrag, bfrag, d, 0, 0, 0);
            ushort4 pk;                               // raw weighted (1/cnt applied in epilogue)
            pk.x = f2bf(d[0]); pk.y = f2bf(d[1]); pk.z = f2bf(d[2]); pk.w = f2bf(d[3]);
            *(ushort4*)&wtw[m * WTP + (ct * 16 + l15) * 16 + lq * 4] = pk;
        }
    }
    __syncthreads();   // the ONLY barrier: weighted rows + inv visible

    // ---- Phase C: out[m][d] = inv[m] * sum_kc weighted[m][kc] * W''[kc][d] ----
    {
        floatx4 acc = {0.f, 0.f, 0.f, 0.f};
        const unsigned short* ap = &wtw[(l15 & 7) * WTP + lq * 8];   // rows 8..15 junk-safe
        const unsigned short* bp = wbf2 + ((size_t)(wv * 32) * 64 + lane) * 8;
#pragma unroll 8
        for (int s = 0; s < 32; s++) {
            const short8 a = lds_load8(ap + s * 32);
            const short8 b = *(const short8*)(bp + s * 512);   // coalesced 1 KB/wave, L2-hot
            acc = __builtin_amdgcn_mfma_f32_16x16x32_bf16(a, b, acc, 0, 0, 0);
        }
        if (lq < 2) {                                 // D rows m = lq*4+r valid for m < 8
            const int d = wv * 16 + l15;
#pragma unroll
            for (int r = 0; r < 4; r++) {
                const int m = lq * 4 + r;
                out[(size_t)(m0 + m) * 64 + d] = acc[r] * inv_lds[m];
            }
        }
    }
}

extern "C" void kernel_launch(void* const* d_in, const int* in_sizes, int n_in,
                              void* d_out, int out_size, void* d_ws, size_t ws_size,
                              hipStream_t stream) {
    const float* q_points = (const float*)d_in[0];
    const float* s_points = (const float*)d_in[1];
    const float* s_feats  = (const float*)d_in[2];
    const int*   nbr      = (const int*)d_in[3];
    const float* weights  = (const float*)d_in[4];
    const float* kpts     = (const float*)d_in[5];
    float* out = (float*)d_out;

    char* ws = (char*)d_ws;
    unsigned short* wbf2 = (unsigned short*)ws;              // [0, 131072)
    float* rowsum = (float*)(ws + 131072);                   // (N+1) floats
    float4* kpp = (float4*)(ws + 531600);                    // 240 B, 16B-aligned
    unsigned short* sfb = (unsigned short*)(ws + 532480);    // (N+1)*64 bf16 = 12.8 MB

    prep_all<<<815, 256, 0, stream>>>(s_feats, weights, kpts, sfb, rowsum, wbf2, kpp);
    kpconv_fused<<<MPTS / TM, 256, 0, stream>>>(q_points, s_points, sfb, nbr,
                                                wbf2, kpp, rowsum, out);
}